// Round 1
// baseline (36052.078 us; speedup 1.0000x reference)
//
#include <hip/hip_runtime.h>

#define NB 128      // batch
#define NT 512      // time steps
#define DIN 256     // layer-0 input dim
#define DD 512      // hidden dim (both layers)

using bf16x8 = __attribute__((ext_vector_type(8))) short;
using f32x4v = __attribute__((ext_vector_type(4))) float;

__device__ __forceinline__ unsigned short f2bf(float f) {
  unsigned int u = __builtin_bit_cast(unsigned int, f);
  u = (u + 0x7fffu + ((u >> 16) & 1u)) >> 16;   // RTN-even
  return (unsigned short)u;
}
__device__ __forceinline__ float bf2f(unsigned short h) {
  unsigned int u = ((unsigned int)h) << 16;
  return __builtin_bit_cast(float, u);
}

// ---------------- prep: cast x -> bf16 hi/lo, zero states & flags ----------------
__global__ void prep_kernel(const float* __restrict__ x,
                            unsigned short* __restrict__ x_hi,
                            unsigned short* __restrict__ x_lo,
                            unsigned int* __restrict__ flags,
                            float* __restrict__ s_f32,
                            unsigned short* __restrict__ s_hi,
                            unsigned short* __restrict__ s_lo) {
  const long stride = (long)gridDim.x * blockDim.x;
  long i = (long)blockIdx.x * blockDim.x + threadIdx.x;
  const long NX = (long)NB * NT * DIN;
  for (long j = i; j < NX; j += stride) {
    float v = x[j];
    unsigned short h = f2bf(v);
    x_hi[j] = h;
    x_lo[j] = f2bf(v - bf2f(h));
  }
  if (i < 256) flags[i] = 0u;                 // barrier flags MUST be re-zeroed (ws poisoned 0xAA)
  const long NS = 2L * NB * DD;               // fp32 master state, both layers
  for (long j = i; j < NS; j += stride) s_f32[j] = 0.f;
  const long NS2 = 2L * NS;                   // bf16 state, both parities x both layers
  for (long j = i; j < NS2; j += stride) { s_hi[j] = 0; s_lo[j] = 0; }
}

// ---------------- device-wide barrier: per-WG flag + per-thread poll ----------------
__device__ __forceinline__ void gbarrier(unsigned int* flags, int bid, unsigned int rnd) {
  __syncthreads();  // drains this WG's vmem (compiler emits vmcnt(0) before s_barrier)
  if (threadIdx.x == 0)
    __hip_atomic_store(&flags[bid], rnd, __ATOMIC_RELEASE, __HIP_MEMORY_SCOPE_AGENT);
  unsigned int v;
  do {
    v = __hip_atomic_load(&flags[threadIdx.x], __ATOMIC_RELAXED, __HIP_MEMORY_SCOPE_AGENT);
    if (v < rnd) __builtin_amdgcn_s_sleep(2);
  } while (v < rnd);
  __syncthreads();
  __threadfence();  // acquire: invalidate L1/L2 before reading other WGs' data
}

// ---------------- K-partial GEMM: split-bf16 A (hi+lo), bf16 B from LDS ----------------
__device__ __forceinline__ void gemm_part(const unsigned short* __restrict__ aHi,
                                          const unsigned short* __restrict__ aLo,
                                          const unsigned short* __restrict__ bCol,
                                          int kn, int quad,
                                          f32x4v& cH0, f32x4v& cL0,
                                          f32x4v& cH1, f32x4v& cL1) {
  const unsigned short* ah = aHi + quad * 8;
  const unsigned short* al = aLo + quad * 8;
  const unsigned short* bb = bCol + quad * 8;
  for (int kk = 0; kk < kn; kk += 64) {     // 4 independent MFMA chains
    bf16x8 a0h = *(const bf16x8*)(ah + kk);
    bf16x8 a0l = *(const bf16x8*)(al + kk);
    bf16x8 b0  = *(const bf16x8*)(bb + kk);
    bf16x8 a1h = *(const bf16x8*)(ah + kk + 32);
    bf16x8 a1l = *(const bf16x8*)(al + kk + 32);
    bf16x8 b1  = *(const bf16x8*)(bb + kk + 32);
    cH0 = __builtin_amdgcn_mfma_f32_16x16x32_bf16(a0h, b0, cH0, 0, 0, 0);
    cL0 = __builtin_amdgcn_mfma_f32_16x16x32_bf16(a0l, b0, cL0, 0, 0, 0);
    cH1 = __builtin_amdgcn_mfma_f32_16x16x32_bf16(a1h, b1, cH1, 0, 0, 0);
    cL1 = __builtin_amdgcn_mfma_f32_16x16x32_bf16(a1l, b1, cL1, 0, 0, 0);
  }
}

// ---------------- persistent GRU kernel ----------------
// 256 WGs x 256 thr, 1 WG/CU (LDS-bound). Super-step s: phase A = zr gates for
// L0@t=s and L1@t=s-1 (all 256 WGs); phase B = candidates+state update (WGs 0..127).
__global__ void __launch_bounds__(256, 1) gru_kernel(
    const float* __restrict__ Wzr0, const float* __restrict__ bzr0,
    const float* __restrict__ Wh0,  const float* __restrict__ bh0,
    const float* __restrict__ Wzr1, const float* __restrict__ bzr1,
    const float* __restrict__ Wh1,  const float* __restrict__ bh1,
    const unsigned short* __restrict__ x_hi, const unsigned short* __restrict__ x_lo,
    float* __restrict__ s_f32, unsigned short* __restrict__ s_hi, unsigned short* __restrict__ s_lo,
    unsigned short* __restrict__ zs_hi, unsigned short* __restrict__ zs_lo,
    float* __restrict__ r_f32,
    unsigned int* flags, float* __restrict__ out)
{
  extern __shared__ __align__(16) unsigned short smem[];
  const int bid = blockIdx.x;
  const int tid = threadIdx.x;
  const int w    = tid >> 6;
  const int lane = tid & 63;
  const int quad = lane >> 4;
  const int l16  = lane & 15;
  const int wr = (w >> 1) << 4;   // wave row offset in 32x32 tile
  const int wc = (w & 1) << 4;    // wave col offset

  // ---- phase A (zr) static config: bid<128 -> layer0, else layer1; 32x32 tiles over [128 x 1024]
  const int lA   = (bid >= 128) ? 1 : 0;
  const int aa   = bid & 127;
  const int colA = (aa & 31) << 5;
  const int rowA = (aa >> 5) << 5;
  const int KA   = lA ? 1024 : 768;
  const int KIA  = lA ? 512 : 256;    // input-part K (x for L0, h0 for L1)
  const int ldaA = KA + 8;            // +8 pad breaks LDS bank aliasing
  const float* WzrA = lA ? Wzr1 : Wzr0;
  const float* bzrA = lA ? bzr1 : bzr0;
  unsigned short* ldsA = smem;        // [32 cols][KA+8] col-major slices

  // ---- phase B (h) static config: bid<64 -> layer0, 64..127 -> layer1; 32x32 over [128 x 512]
  const bool hasB = (bid < 128);
  const int lB   = (bid >= 64) ? 1 : 0;
  const int bb_  = bid & 63;
  const int colB = (bb_ & 15) << 5;
  const int rowB = (bb_ >> 4) << 5;
  const int KB   = lB ? 1024 : 768;
  const int KIB  = lB ? 512 : 256;
  const int ldaB = KB + 8;
  const float* WhB = lB ? Wh1 : Wh0;
  const float* bhB = lB ? bh1 : bh0;
  unsigned short* ldsB = smem + 32 * ldaA;

  // ---- one-time LDS weight fill (f32 -> bf16, transposed to [col][k])
  for (int idx = tid; idx < (KA << 5); idx += 256) {
    int k = idx >> 5, c = idx & 31;
    ldsA[c * ldaA + k] = f2bf(WzrA[k * 1024 + colA + c]);
  }
  if (hasB) {
    for (int idx = tid; idx < (KB << 5); idx += 256) {
      int k = idx >> 5, c = idx & 31;
      ldsB[c * ldaB + k] = f2bf(WhB[k * 512 + colB + c]);
    }
  }
  __syncthreads();

  const float biasA = bzrA[colA + wc + l16];
  const float biasB = hasB ? bhB[colB + wc + l16] : 0.f;

  for (int s = 0; s <= NT; ++s) {
    const int p = (s + 1) & 1;   // read parity for state entering this step

    // ================= phase A: zr = sigmoid([in | state] @ Wzr + b) =================
    const bool actA = lA ? (s >= 1) : (s < NT);
    if (actA) {
      const int t = lA ? (s - 1) : s;
      const int rowFrag = rowA + wr + l16;
      f32x4v c0 = {biasA, biasA, biasA, biasA};
      f32x4v c1 = {0.f,0.f,0.f,0.f}, c2 = {0.f,0.f,0.f,0.f}, c3 = {0.f,0.f,0.f,0.f};
      const unsigned short* bCol = ldsA + (wc + l16) * ldaA;
      const unsigned short *inHi, *inLo;
      if (lA == 0) {
        long off = (long)rowFrag * (NT * DIN) + (long)t * DIN;
        inHi = x_hi + off; inLo = x_lo + off;
      } else {
        long off = ((long)(p * 2 + 0) * NB + rowFrag) * DD;   // h0(t) = layer0 state, parity p
        inHi = s_hi + off; inLo = s_lo + off;
      }
      gemm_part(inHi, inLo, bCol, KIA, quad, c0, c1, c2, c3);
      {
        long off = ((long)(p * 2 + lA) * NB + rowFrag) * DD;  // own recurrent state
        gemm_part(s_hi + off, s_lo + off, bCol + KIA, DD, quad, c0, c1, c2, c3);
      }
      const int colG = colA + wc + l16;
      const int rowE = rowA + wr + (quad << 2);
      #pragma unroll
      for (int i = 0; i < 4; ++i) {
        float pre = c0[i] + c1[i] + c2[i] + c3[i];
        float g = 1.f / (1.f + __expf(-pre));
        int row = rowE + i;
        if (colG < DD) {            // z column -> write z*state (bf16 hi/lo) for phase B
          long sidx = ((long)lA * NB + row) * DD + colG;
          float zs = g * s_f32[sidx];
          unsigned short h = f2bf(zs);
          zs_hi[sidx] = h;
          zs_lo[sidx] = f2bf(zs - bf2f(h));
        } else {                    // r column -> stash fp32 for the state update
          long ridx = ((long)lA * NB + row) * DD + (colG - DD);
          r_f32[ridx] = g;
        }
      }
    }
    gbarrier(flags, bid, (unsigned)(2 * s + 1));

    // ========= phase B: h_tmp = tanh([in | z*s] @ Wh + b); h = r*s + (1-r)*h_tmp =========
    const bool actB = hasB && (lB ? (s >= 1) : (s < NT));
    if (actB) {
      const int t = lB ? (s - 1) : s;
      const int rowFrag = rowB + wr + l16;
      f32x4v c0 = {biasB, biasB, biasB, biasB};
      f32x4v c1 = {0.f,0.f,0.f,0.f}, c2 = {0.f,0.f,0.f,0.f}, c3 = {0.f,0.f,0.f,0.f};
      const unsigned short* bCol = ldsB + (wc + l16) * ldaB;
      const unsigned short *inHi, *inLo;
      if (lB == 0) {
        long off = (long)rowFrag * (NT * DIN) + (long)t * DIN;
        inHi = x_hi + off; inLo = x_lo + off;
      } else {
        long off = ((long)(p * 2 + 0) * NB + rowFrag) * DD;   // h0(t), parity p
        inHi = s_hi + off; inLo = s_lo + off;
      }
      gemm_part(inHi, inLo, bCol, KIB, quad, c0, c1, c2, c3);
      {
        long off = ((long)lB * NB + rowFrag) * DD;            // z*state staged by phase A
        gemm_part(zs_hi + off, zs_lo + off, bCol + KIB, DD, quad, c0, c1, c2, c3);
      }
      const int colG = colB + wc + l16;
      const int rowE = rowB + wr + (quad << 2);
      const int pw = s & 1;        // write parity
      #pragma unroll
      for (int i = 0; i < 4; ++i) {
        float pre = c0[i] + c1[i] + c2[i] + c3[i];
        float ax = fabsf(pre);
        float e  = __expf(-2.f * ax);
        float th = (1.f - e) / (1.f + e);
        th = (pre < 0.f) ? -th : th;
        int row = rowE + i;
        long idx = ((long)lB * NB + row) * DD + colG;
        float rv = r_f32[idx];
        float sv = s_f32[idx];
        float h  = rv * sv + (1.f - rv) * th;
        s_f32[idx] = h;                                        // fp32 master state
        long shidx = ((long)(pw * 2 + lB) * NB + row) * DD + colG;
        unsigned short hh = f2bf(h);
        s_hi[shidx] = hh;
        s_lo[shidx] = f2bf(h - bf2f(hh));
        if (lB) out[((long)row * NT + t) * DD + colG] = h;     // layer-1 output
      }
    }
    gbarrier(flags, bid, (unsigned)(2 * s + 2));
  }
}

// ---------------- host ----------------
extern "C" void kernel_launch(void* const* d_in, const int* in_sizes, int n_in,
                              void* d_out, int out_size, void* d_ws, size_t ws_size,
                              hipStream_t stream) {
  const float* x    = (const float*)d_in[0];
  const float* Wzr0 = (const float*)d_in[1];
  const float* bzr0 = (const float*)d_in[2];
  const float* Wh0  = (const float*)d_in[3];
  const float* bh0  = (const float*)d_in[4];
  const float* Wzr1 = (const float*)d_in[5];
  const float* bzr1 = (const float*)d_in[6];
  const float* Wh1  = (const float*)d_in[7];
  const float* bh1  = (const float*)d_in[8];
  float* out = (float*)d_out;

  char* pp = (char*)d_ws;
  unsigned int* flags = (unsigned int*)pp;          pp += 4096;
  unsigned short* x_hi = (unsigned short*)pp;       pp += (size_t)NB * NT * DIN * 2;
  unsigned short* x_lo = (unsigned short*)pp;       pp += (size_t)NB * NT * DIN * 2;
  float* s_f32 = (float*)pp;                        pp += (size_t)2 * NB * DD * 4;
  unsigned short* s_hi = (unsigned short*)pp;       pp += (size_t)4 * NB * DD * 2;  // [parity][layer]
  unsigned short* s_lo = (unsigned short*)pp;       pp += (size_t)4 * NB * DD * 2;
  unsigned short* zs_hi = (unsigned short*)pp;      pp += (size_t)2 * NB * DD * 2;
  unsigned short* zs_lo = (unsigned short*)pp;      pp += (size_t)2 * NB * DD * 2;
  float* r_f32 = (float*)pp;                        pp += (size_t)2 * NB * DD * 4;

  hipLaunchKernelGGL(prep_kernel, dim3(1024), dim3(256), 0, stream,
                     x, x_hi, x_lo, flags, s_f32, s_hi, s_lo);

  const int SMEM = 32 * (768 + 8) * 2 + 32 * (1024 + 8) * 2;   // 115712 B, worst-case WG
  (void)hipFuncSetAttribute((const void*)gru_kernel,
                            hipFuncAttributeMaxDynamicSharedMemorySize, SMEM);
  // grid 256 WGs x 256 thr: LDS forces 1 WG/CU -> all 256 co-resident on 256 CUs,
  // so the flag barrier cannot deadlock without a cooperative launch.
  hipLaunchKernelGGL(gru_kernel, dim3(256), dim3(256), SMEM, stream,
                     Wzr0, bzr0, Wh0, bh0, Wzr1, bzr1, Wh1, bh1,
                     x_hi, x_lo, s_f32, s_hi, s_lo, zs_hi, zs_lo, r_f32, flags, out);
}

// Round 2
// 26572.772 us; speedup vs baseline: 1.3567x; 1.3567x over previous
//
#include <hip/hip_runtime.h>

#define NB 128      // batch
#define NT 512      // time steps
#define DIN 256     // layer-0 input dim
#define DD 512      // hidden dim

using bf16x8 = __attribute__((ext_vector_type(8))) short;
using f32x4v = __attribute__((ext_vector_type(4))) float;

__device__ __forceinline__ unsigned short f2bf(float f) {
  unsigned int u = __builtin_bit_cast(unsigned int, f);
  u = (u + 0x7fffu + ((u >> 16) & 1u)) >> 16;
  return (unsigned short)u;
}
__device__ __forceinline__ float bf2f(unsigned short h) {
  unsigned int u = ((unsigned int)h) << 16;
  return __builtin_bit_cast(float, u);
}
// pack fp32 -> (bf16 hi | bf16 lo) in one dword: split-bf16 keeps recurrence accurate
__device__ __forceinline__ unsigned int packf(float v) {
  unsigned short hi = f2bf(v);
  unsigned short lo = f2bf(v - bf2f(hi));
  return (((unsigned int)hi) << 16) | lo;
}

// ---------------- prep: pack x, zero state parities & group counters ----------------
__global__ void prep_kernel(const float* __restrict__ x, unsigned int* __restrict__ x_pk,
                            unsigned int* __restrict__ hp, unsigned int* __restrict__ cnt) {
  long i = (long)blockIdx.x * blockDim.x + threadIdx.x;
  const long stride = (long)gridDim.x * blockDim.x;
  const long NX = (long)NB * NT * DIN;
  for (long j = i; j < NX; j += stride) x_pk[j] = packf(x[j]);
  const long NH = 2L * 2 * NB * DD;              // [parity][layer][row][col]
  for (long j = i; j < NH; j += stride) hp[j] = 0u;
  if (i < 256) cnt[i] = 0u;                      // re-zero every launch (ws poisoned 0xAA)
}

__device__ __forceinline__ void unpack8(const unsigned int* d, bf16x8& hi, bf16x8& lo) {
  #pragma unroll
  for (int j = 0; j < 8; ++j) {
    hi[j] = (short)(d[j] >> 16);
    lo[j] = (short)(d[j] & 0xffffu);
  }
}

// GEMM over K-range from packed-uint A (atomic = coherent cross-WG data) and bf16 B in LDS.
// 4 chains (2 k-streams x hi/lo) for MFMA ILP. KN literal at call sites -> full unroll,
// loads hoisted ahead of MFMAs (launch_bounds(256,1) allows up to 512 VGPRs).
template<int KN, bool AT>
__device__ __forceinline__ void gemm_pk(const unsigned int* __restrict__ a,
                                        const unsigned short* __restrict__ b,
                                        int quad, f32x4v& cH0, f32x4v& cL0,
                                        f32x4v& cH1, f32x4v& cL1) {
  const unsigned int* ap = a + quad * 8;
  const unsigned short* bp = b + quad * 8;
  #pragma unroll
  for (int kk = 0; kk < KN; kk += 64) {
    unsigned int d0[8], d1[8];
    #pragma unroll
    for (int j = 0; j < 8; ++j) {
      if (AT) {
        d0[j] = __hip_atomic_load(ap + kk + j,      __ATOMIC_RELAXED, __HIP_MEMORY_SCOPE_AGENT);
        d1[j] = __hip_atomic_load(ap + kk + 32 + j, __ATOMIC_RELAXED, __HIP_MEMORY_SCOPE_AGENT);
      } else {
        d0[j] = ap[kk + j];
        d1[j] = ap[kk + 32 + j];
      }
    }
    bf16x8 a0h, a0l, a1h, a1l;
    unpack8(d0, a0h, a0l);
    unpack8(d1, a1h, a1l);
    bf16x8 b0 = *(const bf16x8*)(bp + kk);
    bf16x8 b1 = *(const bf16x8*)(bp + kk + 32);
    cH0 = __builtin_amdgcn_mfma_f32_16x16x32_bf16(a0h, b0, cH0, 0, 0, 0);
    cL0 = __builtin_amdgcn_mfma_f32_16x16x32_bf16(a0l, b0, cL0, 0, 0, 0);
    cH1 = __builtin_amdgcn_mfma_f32_16x16x32_bf16(a1h, b1, cH1, 0, 0, 0);
    cL1 = __builtin_amdgcn_mfma_f32_16x16x32_bf16(a1l, b1, cL1, 0, 0, 0);
  }
}

// ---------------- persistent GRU ----------------
// 256 WGs x 256 thr, 1 WG/CU. WG (l, rb, cb) owns rows [32rb,32rb+32), h/z/r cols
// [16cb,16cb+16) of layer l. 4 independent rb-groups of 64 WGs; 2 group barriers
// per super-step. All cross-WG data = relaxed AGENT atomic dwords (no cache flushes).
__global__ void __launch_bounds__(256, 1) gru_kernel(
    const float* __restrict__ Wzr0, const float* __restrict__ bzr0,
    const float* __restrict__ Wh0,  const float* __restrict__ bh0,
    const float* __restrict__ Wzr1, const float* __restrict__ bzr1,
    const float* __restrict__ Wh1,  const float* __restrict__ bh1,
    const unsigned int* __restrict__ x_pk, unsigned int* __restrict__ hp,
    unsigned int* __restrict__ zs, unsigned int* __restrict__ cnt,
    float* __restrict__ out)
{
  extern __shared__ __align__(16) unsigned char smem[];
  const int bid = blockIdx.x, tid = threadIdx.x;
  const int w = tid >> 6, lane = tid & 63, quad = lane >> 4, l16 = lane & 15;
  const int l  = bid >> 7;          // layer
  const int rb = (bid >> 5) & 3;    // row block (sync group)
  const int cb = bid & 31;          // column block
  const int r0 = rb << 5;
  const int c0 = cb << 4;
  const int K  = l ? 1024 : 768;
  const int KI = l ? 512 : 256;     // input-part K (x for L0, h0 for L1)
  const int ldw = K + 8;            // +8 shorts: 2-way-max LDS bank aliasing (free)

  unsigned short* wlds = (unsigned short*)smem;                 // [48 cols][ldw]: z(16) r(16) h(16)
  float* s_lds = (float*)(smem + ((48 * ldw * 2 + 15) & ~15));  // [32][16] fp32 master state
  float* r_lds = s_lds + 512;                                   // [32][16] r gate
  float* pscr  = r_lds + 512;                                   // [2][16][16] phase-B partials

  const float* Wzr = l ? Wzr1 : Wzr0;
  const float* Wh  = l ? Wh1 : Wh0;
  for (int idx = tid; idx < 16 * K; idx += 256) {
    int j = idx / K, k = idx - j * K;
    wlds[j * ldw + k]        = f2bf(Wzr[k * (2 * DD) + c0 + j]);        // z cols
    wlds[(16 + j) * ldw + k] = f2bf(Wzr[k * (2 * DD) + DD + c0 + j]);   // r cols
    wlds[(32 + j) * ldw + k] = f2bf(Wh[k * DD + c0 + j]);               // h cols
  }
  for (int idx = tid; idx < 512; idx += 256) s_lds[idx] = 0.f;
  const float bz = (l ? bzr1 : bzr0)[c0 + l16];
  const float br = (l ? bzr1 : bzr0)[DD + c0 + l16];
  const float bh = (l ? bh1 : bh0)[c0 + l16];
  __syncthreads();

  unsigned int* myc = cnt + rb * 32;   // group counter, own cache line
  unsigned int rnd = 0;

  for (int s = 0; s <= NT; ++s) {
    const int p  = (s + 1) & 1;        // read parity
    const int pw = s & 1;              // write parity
    const bool act = l ? (s >= 1) : (s < NT);
    const int t = l ? (s - 1) : s;

    // ============ phase A: zr = sigmoid([in | h] Wzr + b); stage z*s, keep r local ============
    if (act) {
      const int rowHalf = w >> 1, isR = w & 1;   // waves 0,2: z; 1,3: r
      const int gRow = r0 + (rowHalf << 4) + l16;
      f32x4v cH0 = {0,0,0,0}, cL0 = {0,0,0,0}, cH1 = {0,0,0,0}, cL1 = {0,0,0,0};
      const unsigned short* bseg = wlds + (isR * 16 + l16) * ldw;
      if (l == 0) {
        const unsigned int* xa = x_pk + ((long)gRow * NT + t) * DIN;
        gemm_pk<256, false>(xa, bseg, quad, cH0, cL0, cH1, cL1);
        const unsigned int* ha = hp + ((p * 2 + 0) * NB + gRow) * DD;
        gemm_pk<512, true>(ha, bseg + 256, quad, cH0, cL0, cH1, cL1);
      } else {
        const unsigned int* h0a = hp + ((p * 2 + 0) * NB + gRow) * DD;
        gemm_pk<512, true>(h0a, bseg, quad, cH0, cL0, cH1, cL1);
        const unsigned int* h1a = hp + ((p * 2 + 1) * NB + gRow) * DD;
        gemm_pk<512, true>(h1a, bseg + 512, quad, cH0, cL0, cH1, cL1);
      }
      #pragma unroll
      for (int i = 0; i < 4; ++i) {
        float pre = (cH0[i] + cL0[i]) + (cH1[i] + cL1[i]) + (isR ? br : bz);
        float g = 1.f / (1.f + __expf(-pre));
        int rloc = (rowHalf << 4) + (quad << 2) + i;
        if (!isR) {
          float sv = s_lds[rloc * 16 + l16];
          __hip_atomic_store(&zs[((long)l * NB + r0 + rloc) * DD + c0 + l16],
                             packf(g * sv), __ATOMIC_RELAXED, __HIP_MEMORY_SCOPE_AGENT);
        } else {
          r_lds[rloc * 16 + l16] = g;
        }
      }
    }
    ++rnd;
    __syncthreads();   // emits s_waitcnt vmcnt(0): all atomic stores coherent before arrive
    if (tid == 0) {
      __hip_atomic_fetch_add(myc, 1u, __ATOMIC_RELAXED, __HIP_MEMORY_SCOPE_AGENT);
      const unsigned int tgt = 64u * rnd;
      while (__hip_atomic_load(myc, __ATOMIC_RELAXED, __HIP_MEMORY_SCOPE_AGENT) < tgt)
        __builtin_amdgcn_s_sleep(1);
    }
    __syncthreads();

    // ============ phase B: h = r*s + (1-r)*tanh([in | z*s] Wh + b) ============
    if (act) {
      const int rowHalf = w & 1, src = w >> 1;   // waves 0,1: input-K; 2,3: zs-K
      const int gRow = r0 + (rowHalf << 4) + l16;
      f32x4v cH0 = {0,0,0,0}, cL0 = {0,0,0,0}, cH1 = {0,0,0,0}, cL1 = {0,0,0,0};
      const unsigned short* hseg = wlds + (32 + l16) * ldw;
      if (src == 0) {
        if (l == 0) {
          const unsigned int* xa = x_pk + ((long)gRow * NT + t) * DIN;
          gemm_pk<256, false>(xa, hseg, quad, cH0, cL0, cH1, cL1);
        } else {
          const unsigned int* h0a = hp + ((p * 2 + 0) * NB + gRow) * DD;
          gemm_pk<512, true>(h0a, hseg, quad, cH0, cL0, cH1, cL1);
        }
      } else {
        const unsigned int* za = zs + ((long)l * NB + gRow) * DD;
        gemm_pk<512, true>(za, hseg + KI, quad, cH0, cL0, cH1, cL1);
      }
      f32x4v tot;
      #pragma unroll
      for (int i = 0; i < 4; ++i) tot[i] = (cH0[i] + cL0[i]) + (cH1[i] + cL1[i]);
      if (src == 1) {
        #pragma unroll
        for (int i = 0; i < 4; ++i)
          pscr[rowHalf * 256 + ((quad << 2) + i) * 16 + l16] = tot[i];
      }
      __syncthreads();   // act is WG-uniform -> legal
      if (src == 0) {
        #pragma unroll
        for (int i = 0; i < 4; ++i) {
          int rloc = (rowHalf << 4) + (quad << 2) + i;
          float pre = tot[i] + pscr[rowHalf * 256 + ((quad << 2) + i) * 16 + l16] + bh;
          float ax = fabsf(pre), e = __expf(-2.f * ax);
          float th = (1.f - e) / (1.f + e);
          th = (pre < 0.f) ? -th : th;
          float rv = r_lds[rloc * 16 + l16];
          float sv = s_lds[rloc * 16 + l16];
          float h = rv * sv + (1.f - rv) * th;
          s_lds[rloc * 16 + l16] = h;
          __hip_atomic_store(&hp[((pw * 2 + l) * NB + r0 + rloc) * DD + c0 + l16],
                             packf(h), __ATOMIC_RELAXED, __HIP_MEMORY_SCOPE_AGENT);
          if (l) out[((long)(r0 + rloc) * NT + t) * DD + c0 + l16] = h;
        }
      }
    }
    ++rnd;
    __syncthreads();
    if (tid == 0) {
      __hip_atomic_fetch_add(myc, 1u, __ATOMIC_RELAXED, __HIP_MEMORY_SCOPE_AGENT);
      const unsigned int tgt = 64u * rnd;
      while (__hip_atomic_load(myc, __ATOMIC_RELAXED, __HIP_MEMORY_SCOPE_AGENT) < tgt)
        __builtin_amdgcn_s_sleep(1);
    }
    __syncthreads();
  }
}

// ---------------- host ----------------
extern "C" void kernel_launch(void* const* d_in, const int* in_sizes, int n_in,
                              void* d_out, int out_size, void* d_ws, size_t ws_size,
                              hipStream_t stream) {
  const float* x    = (const float*)d_in[0];
  const float* Wzr0 = (const float*)d_in[1];
  const float* bzr0 = (const float*)d_in[2];
  const float* Wh0  = (const float*)d_in[3];
  const float* bh0  = (const float*)d_in[4];
  const float* Wzr1 = (const float*)d_in[5];
  const float* bzr1 = (const float*)d_in[6];
  const float* Wh1  = (const float*)d_in[7];
  const float* bh1  = (const float*)d_in[8];
  float* out = (float*)d_out;

  char* pp = (char*)d_ws;
  unsigned int* cnt  = (unsigned int*)pp;  pp += 1024;
  unsigned int* x_pk = (unsigned int*)pp;  pp += (size_t)NB * NT * DIN * 4;  // packed hi|lo
  unsigned int* hp   = (unsigned int*)pp;  pp += (size_t)2 * 2 * NB * DD * 4;
  unsigned int* zs   = (unsigned int*)pp;  pp += (size_t)2 * NB * DD * 4;

  hipLaunchKernelGGL(prep_kernel, dim3(1024), dim3(256), 0, stream, x, x_pk, hp, cnt);

  const int SMEM = ((48 * (1024 + 8) * 2 + 15) & ~15) + 3 * 512 * 4;  // 105216 B
  (void)hipFuncSetAttribute((const void*)gru_kernel,
                            hipFuncAttributeMaxDynamicSharedMemorySize, SMEM);
  // 256 WGs x 256 thr, >80 KB LDS each -> exactly 1 WG/CU, all co-resident (no deadlock)
  hipLaunchKernelGGL(gru_kernel, dim3(256), dim3(256), SMEM, stream,
                     Wzr0, bzr0, Wh0, bh0, Wzr1, bzr1, Wh1, bh1,
                     x_pk, hp, zs, cnt, out);
}

// Round 3
// 10507.487 us; speedup vs baseline: 3.4311x; 2.5289x over previous
//
#include <hip/hip_runtime.h>

#define NB 128      // batch
#define NT 512      // time steps
#define DIN 256     // layer-0 input dim
#define DD 512      // hidden dim

using bf16x8 = __attribute__((ext_vector_type(8))) short;
using f32x4v = __attribute__((ext_vector_type(4))) float;
using u32x4  = __attribute__((ext_vector_type(4))) unsigned int;

__device__ __forceinline__ unsigned short f2bf(float f) {
  unsigned int u = __builtin_bit_cast(unsigned int, f);
  u = (u + 0x7fffu + ((u >> 16) & 1u)) >> 16;
  return (unsigned short)u;
}
__device__ __forceinline__ float bf2f(unsigned short h) {
  unsigned int u = ((unsigned int)h) << 16;
  return __builtin_bit_cast(float, u);
}
// pack fp32 -> (bf16 hi | bf16 lo) in one dword: split-bf16 keeps the 512-step recurrence accurate
__device__ __forceinline__ unsigned int packf(float v) {
  unsigned short hi = f2bf(v);
  unsigned short lo = f2bf(v - bf2f(hi));
  return (((unsigned int)hi) << 16) | lo;
}

// ---------------- prep: pack x, zero state parities & group counters ----------------
__global__ void prep_kernel(const float* __restrict__ x, unsigned int* __restrict__ x_pk,
                            unsigned int* __restrict__ hp, unsigned int* __restrict__ cnt) {
  long i = (long)blockIdx.x * blockDim.x + threadIdx.x;
  const long stride = (long)gridDim.x * blockDim.x;
  const long NX = (long)NB * NT * DIN;
  for (long j = i; j < NX; j += stride) x_pk[j] = packf(x[j]);
  const long NH = 2L * 2 * NB * DD;              // [parity][layer][row][col]
  for (long j = i; j < NH; j += stride) hp[j] = 0u;
  if (i < 256) cnt[i] = 0u;                      // re-zero every launch (ws poisoned 0xAA)
}

__device__ __forceinline__ void unpack16(const u32x4& q0, const u32x4& q1,
                                         bf16x8& hi, bf16x8& lo) {
  #pragma unroll
  for (int j = 0; j < 4; ++j) {
    hi[j]     = (short)(q0[j] >> 16);
    lo[j]     = (short)(q0[j] & 0xffffu);
    hi[4 + j] = (short)(q1[j] >> 16);
    lo[4 + j] = (short)(q1[j] & 0xffffu);
  }
}

// K-partial GEMM: packed-uint A via PLAIN coalesced dwordx4 loads (coherence comes from the
// barrier's acquire->buffer_inv), bf16 B from LDS. 4 MFMA chains (2 k-streams x hi/lo) for ILP.
template<int KN>
__device__ __forceinline__ void gemm_pk(const unsigned int* __restrict__ a,
                                        const unsigned short* __restrict__ b,
                                        int quad, f32x4v& cH0, f32x4v& cL0,
                                        f32x4v& cH1, f32x4v& cL1) {
  const unsigned int* ap = a + quad * 8;
  const unsigned short* bp = b + quad * 8;
  #pragma unroll
  for (int kk = 0; kk < KN; kk += 64) {
    u32x4 q0 = *(const u32x4*)(ap + kk);
    u32x4 q1 = *(const u32x4*)(ap + kk + 4);
    u32x4 q2 = *(const u32x4*)(ap + kk + 32);
    u32x4 q3 = *(const u32x4*)(ap + kk + 36);
    bf16x8 a0h, a0l, a1h, a1l;
    unpack16(q0, q1, a0h, a0l);
    unpack16(q2, q3, a1h, a1l);
    bf16x8 b0 = *(const bf16x8*)(bp + kk);
    bf16x8 b1 = *(const bf16x8*)(bp + kk + 32);
    cH0 = __builtin_amdgcn_mfma_f32_16x16x32_bf16(a0h, b0, cH0, 0, 0, 0);
    cL0 = __builtin_amdgcn_mfma_f32_16x16x32_bf16(a0l, b0, cL0, 0, 0, 0);
    cH1 = __builtin_amdgcn_mfma_f32_16x16x32_bf16(a1h, b1, cH1, 0, 0, 0);
    cL1 = __builtin_amdgcn_mfma_f32_16x16x32_bf16(a1l, b1, cL1, 0, 0, 0);
  }
}

// Group barrier. Release: __syncthreads drains vmem (vmcnt(0)) -> atomic stores are at LLC
// before the relaxed counter add. Acquire: after the poll succeeds, ONE acquire atomic load
// makes the compiler emit buffer_inv (L1+L2 invalidate, dirty lines kept) so the post-barrier
// PLAIN loads fetch fresh data from LLC. One cache-op per WG per phase.
__device__ __forceinline__ void gbarrier(unsigned int* myc, int tid, unsigned int tgt) {
  __syncthreads();
  if (tid == 0) {
    __hip_atomic_fetch_add(myc, 1u, __ATOMIC_RELAXED, __HIP_MEMORY_SCOPE_AGENT);
    while (__hip_atomic_load(myc, __ATOMIC_RELAXED, __HIP_MEMORY_SCOPE_AGENT) < tgt)
      __builtin_amdgcn_s_sleep(1);
    (void)__hip_atomic_load(myc, __ATOMIC_ACQUIRE, __HIP_MEMORY_SCOPE_AGENT);
  }
  __syncthreads();
}

// ---------------- persistent GRU ----------------
// 256 WGs x 256 thr, 1 WG/CU. WG (l, rb, cb) owns rows [32rb,32rb+32), h/z/r cols
// [16cb,16cb+16) of layer l. 4 independent rb-groups of 64 WGs; 2 group barriers/super-step.
__global__ void __launch_bounds__(256, 1) gru_kernel(
    const float* __restrict__ Wzr0, const float* __restrict__ bzr0,
    const float* __restrict__ Wh0,  const float* __restrict__ bh0,
    const float* __restrict__ Wzr1, const float* __restrict__ bzr1,
    const float* __restrict__ Wh1,  const float* __restrict__ bh1,
    const unsigned int* __restrict__ x_pk, unsigned int* __restrict__ hp,
    unsigned int* __restrict__ zs, unsigned int* __restrict__ cnt,
    float* __restrict__ out)
{
  extern __shared__ __align__(16) unsigned char smem[];
  const int bid = blockIdx.x, tid = threadIdx.x;
  const int w = tid >> 6, lane = tid & 63, quad = lane >> 4, l16 = lane & 15;
  const int l  = bid >> 7;          // layer
  const int rb = (bid >> 5) & 3;    // row block (sync group)
  const int cb = bid & 31;          // column block
  const int r0 = rb << 5;
  const int c0 = cb << 4;
  const int K  = l ? 1024 : 768;
  const int KI = l ? 512 : 256;     // input-part K (x for L0, h0 for L1)
  const int ldw = K + 8;            // +8 shorts padding

  unsigned short* wlds = (unsigned short*)smem;                 // [48 cols][ldw]: z(16) r(16) h(16)
  float* s_lds = (float*)(smem + ((48 * ldw * 2 + 15) & ~15));  // [32][16] fp32 master state
  float* r_lds = s_lds + 512;                                   // [32][16] r gate
  float* pscr  = r_lds + 512;                                   // [2][16][16] phase-B partials

  const float* Wzr = l ? Wzr1 : Wzr0;
  const float* Wh  = l ? Wh1 : Wh0;
  for (int idx = tid; idx < 16 * K; idx += 256) {
    int j = idx / K, k = idx - j * K;
    wlds[j * ldw + k]        = f2bf(Wzr[k * (2 * DD) + c0 + j]);        // z cols
    wlds[(16 + j) * ldw + k] = f2bf(Wzr[k * (2 * DD) + DD + c0 + j]);   // r cols
    wlds[(32 + j) * ldw + k] = f2bf(Wh[k * DD + c0 + j]);               // h cols
  }
  for (int idx = tid; idx < 512; idx += 256) s_lds[idx] = 0.f;
  const float bz = (l ? bzr1 : bzr0)[c0 + l16];
  const float br = (l ? bzr1 : bzr0)[DD + c0 + l16];
  const float bh = (l ? bh1 : bh0)[c0 + l16];
  __syncthreads();

  unsigned int* myc = cnt + rb * 32;   // per-group counter, own cache line
  unsigned int rnd = 0;

  for (int s = 0; s <= NT; ++s) {
    const int p  = (s + 1) & 1;        // read parity
    const int pw = s & 1;              // write parity
    const bool act = l ? (s >= 1) : (s < NT);
    const int t = l ? (s - 1) : s;

    // ============ phase A: zr = sigmoid([in | h] Wzr + b); stage z*s, keep r local ============
    if (act) {
      const int rowHalf = w >> 1, isR = w & 1;   // waves 0,2: z; 1,3: r
      const int gRow = r0 + (rowHalf << 4) + l16;
      f32x4v cH0 = {0,0,0,0}, cL0 = {0,0,0,0}, cH1 = {0,0,0,0}, cL1 = {0,0,0,0};
      const unsigned short* bseg = wlds + (isR * 16 + l16) * ldw;
      if (l == 0) {
        const unsigned int* xa = x_pk + ((long)gRow * NT + t) * DIN;
        gemm_pk<256>(xa, bseg, quad, cH0, cL0, cH1, cL1);
        const unsigned int* ha = hp + ((p * 2 + 0) * NB + gRow) * DD;
        gemm_pk<512>(ha, bseg + 256, quad, cH0, cL0, cH1, cL1);
      } else {
        const unsigned int* h0a = hp + ((p * 2 + 0) * NB + gRow) * DD;
        gemm_pk<512>(h0a, bseg, quad, cH0, cL0, cH1, cL1);
        const unsigned int* h1a = hp + ((p * 2 + 1) * NB + gRow) * DD;
        gemm_pk<512>(h1a, bseg + 512, quad, cH0, cL0, cH1, cL1);
      }
      #pragma unroll
      for (int i = 0; i < 4; ++i) {
        float pre = (cH0[i] + cL0[i]) + (cH1[i] + cL1[i]) + (isR ? br : bz);
        float g = 1.f / (1.f + __expf(-pre));
        int rloc = (rowHalf << 4) + (quad << 2) + i;
        if (!isR) {
          float sv = s_lds[rloc * 16 + l16];
          __hip_atomic_store(&zs[((long)l * NB + r0 + rloc) * DD + c0 + l16],
                             packf(g * sv), __ATOMIC_RELAXED, __HIP_MEMORY_SCOPE_AGENT);
        } else {
          r_lds[rloc * 16 + l16] = g;
        }
      }
    }
    ++rnd;
    gbarrier(myc, tid, 64u * rnd);

    // ============ phase B: h = r*s + (1-r)*tanh([in | z*s] Wh + b) ============
    if (act) {
      const int rowHalf = w & 1, src = w >> 1;   // waves 0,1: input-K; 2,3: zs-K
      const int gRow = r0 + (rowHalf << 4) + l16;
      f32x4v cH0 = {0,0,0,0}, cL0 = {0,0,0,0}, cH1 = {0,0,0,0}, cL1 = {0,0,0,0};
      const unsigned short* hseg = wlds + (32 + l16) * ldw;
      if (src == 0) {
        if (l == 0) {
          const unsigned int* xa = x_pk + ((long)gRow * NT + t) * DIN;
          gemm_pk<256>(xa, hseg, quad, cH0, cL0, cH1, cL1);
        } else {
          const unsigned int* h0a = hp + ((p * 2 + 0) * NB + gRow) * DD;
          gemm_pk<512>(h0a, hseg, quad, cH0, cL0, cH1, cL1);
        }
      } else {
        const unsigned int* za = zs + ((long)l * NB + gRow) * DD;
        gemm_pk<512>(za, hseg + KI, quad, cH0, cL0, cH1, cL1);
      }
      f32x4v tot;
      #pragma unroll
      for (int i = 0; i < 4; ++i) tot[i] = (cH0[i] + cL0[i]) + (cH1[i] + cL1[i]);
      if (src == 1) {
        #pragma unroll
        for (int i = 0; i < 4; ++i)
          pscr[rowHalf * 256 + ((quad << 2) + i) * 16 + l16] = tot[i];
      }
      __syncthreads();   // act is WG-uniform -> legal
      if (src == 0) {
        #pragma unroll
        for (int i = 0; i < 4; ++i) {
          int rloc = (rowHalf << 4) + (quad << 2) + i;
          float pre = tot[i] + pscr[rowHalf * 256 + ((quad << 2) + i) * 16 + l16] + bh;
          float ax = fabsf(pre), e = __expf(-2.f * ax);
          float th = (1.f - e) / (1.f + e);
          th = (pre < 0.f) ? -th : th;
          float rv = r_lds[rloc * 16 + l16];
          float sv = s_lds[rloc * 16 + l16];
          float h = rv * sv + (1.f - rv) * th;
          s_lds[rloc * 16 + l16] = h;
          __hip_atomic_store(&hp[((pw * 2 + l) * NB + r0 + rloc) * DD + c0 + l16],
                             packf(h), __ATOMIC_RELAXED, __HIP_MEMORY_SCOPE_AGENT);
          if (l) out[((long)(r0 + rloc) * NT + t) * DD + c0 + l16] = h;
        }
      }
    }
    ++rnd;
    gbarrier(myc, tid, 64u * rnd);
  }
}

// ---------------- host ----------------
extern "C" void kernel_launch(void* const* d_in, const int* in_sizes, int n_in,
                              void* d_out, int out_size, void* d_ws, size_t ws_size,
                              hipStream_t stream) {
  const float* x    = (const float*)d_in[0];
  const float* Wzr0 = (const float*)d_in[1];
  const float* bzr0 = (const float*)d_in[2];
  const float* Wh0  = (const float*)d_in[3];
  const float* bh0  = (const float*)d_in[4];
  const float* Wzr1 = (const float*)d_in[5];
  const float* bzr1 = (const float*)d_in[6];
  const float* Wh1  = (const float*)d_in[7];
  const float* bh1  = (const float*)d_in[8];
  float* out = (float*)d_out;

  char* pp = (char*)d_ws;
  unsigned int* cnt  = (unsigned int*)pp;  pp += 1024;
  unsigned int* x_pk = (unsigned int*)pp;  pp += (size_t)NB * NT * DIN * 4;  // packed hi|lo
  unsigned int* hp   = (unsigned int*)pp;  pp += (size_t)2 * 2 * NB * DD * 4;
  unsigned int* zs   = (unsigned int*)pp;  pp += (size_t)2 * NB * DD * 4;

  hipLaunchKernelGGL(prep_kernel, dim3(1024), dim3(256), 0, stream, x, x_pk, hp, cnt);

  const int SMEM = ((48 * (1024 + 8) * 2 + 15) & ~15) + 3 * 512 * 4;  // 105216 B
  (void)hipFuncSetAttribute((const void*)gru_kernel,
                            hipFuncAttributeMaxDynamicSharedMemorySize, SMEM);
  // 256 WGs x 256 thr, >80 KB LDS each -> exactly 1 WG/CU, all co-resident (no deadlock)
  hipLaunchKernelGGL(gru_kernel, dim3(256), dim3(256), SMEM, stream,
                     Wzr0, bzr0, Wh0, bh0, Wzr1, bzr1, Wh1, bh1,
                     x_pk, hp, zs, cnt, out);
}